// Round 11
// baseline (265.939 us; speedup 1.0000x reference)
//
#include <hip/hip_runtime.h>
#include <hip/hip_bf16.h>

typedef float    f32x4  __attribute__((ext_vector_type(4)));
typedef float    f32x16 __attribute__((ext_vector_type(16)));
typedef _Float16 f16x8  __attribute__((ext_vector_type(8)));
typedef _Float16 f16x4  __attribute__((ext_vector_type(4)));
typedef _Float16 f16x2  __attribute__((ext_vector_type(2)));

#define XP 132   // xs plane-pitch: row stride 66 words === 2 mod 32 -> 2-way (free)

// ---------------------------------------------------------------------------
// Kernel 0: W [144][256] f32 -> wt [co(256)][tap(9)][kd(16)] fp16
// k' = tap*16 + kd ordering, matching the A-side fragment reads.
// ---------------------------------------------------------------------------
__global__ __launch_bounds__(256) void prep_wt_kernel(
    const float* __restrict__ W, _Float16* __restrict__ wt)
{
    const int k = blockIdx.x;      // 0..143 ; kd = k/9, tap = k%9
    const int t = threadIdx.x;     // co
    wt[t * 144 + (k % 9) * 16 + (k / 9)] = (_Float16)W[k * 256 + t];
}

// ---------------------------------------------------------------------------
// Fused kernel: block = (b,h), 512 threads. Conv via MFMA; votes stay in
// REGISTERS (each lane's MFMA acc = votes[all d][its 16 w][its co]).
// Routing: phase B = register FMAs; squash via shfl_xor(32); phase C =
// thread-local products + 4-stage shfl_xor butterfly over the 16-lane
// a-group + predicated fp32 logit writes. LDS = 28.5 KB -> 2 blocks/CU.
// ---------------------------------------------------------------------------
__global__ __launch_bounds__(512, 4) void fused_kernel(
    const float* __restrict__ x, const _Float16* __restrict__ wt,
    const float* __restrict__ bias, float* __restrict__ out)
{
    const int h = blockIdx.x;   // 30
    const int b = blockIdx.y;   // 32
    const int t = threadIdx.x;  // 0..511

    __shared__ union {
        _Float16 xs[3][36][XP];             // 28,512 B (conv phase)
        struct {                            // routing phase
            float    logits[8 * 16 * 31];   // 15,872 B (pitch 31)
            _Float16 route16[8 * 16 * 30];  //  7,680 B
        } rt;
    } u;

    // ---- stage x: rows h..h+2, 32 cols, 128 planes; fp16, plane-innermost
    {
        const float* xb = x + (size_t)b * 131072;
        for (int j = t; j < 3 * 4 * XP; j += 512) {      // zero cols 32..35
            int r = j / (4 * XP), rem = j - r * (4 * XP);
            int c = rem / XP, p = rem - c * XP;
            u.xs[r][32 + c][p] = (_Float16)0.f;
        }
        #pragma unroll
        for (int j = 0; j < 6; ++j) {
            int idx = t + j * 512;          // 0..3071 float4 granules
            int p   = idx / 24;             // plane (d*16+kd)
            int rem = idx - p * 24;
            int r   = rem >> 3;             // row 0..2
            int c4  = rem & 7;              // col quad
            f32x4 v = *(const f32x4*)(xb + p * 1024 + (h + r) * 32 + c4 * 4);
            u.xs[r][c4 * 4 + 0][p] = (_Float16)v[0];
            u.xs[r][c4 * 4 + 1][p] = (_Float16)v[1];
            u.xs[r][c4 * 4 + 2][p] = (_Float16)v[2];
            u.xs[r][c4 * 4 + 3][p] = (_Float16)v[3];
        }
    }
    __syncthreads();

    const int lane = t & 63, wv = t >> 6;
    const int l31  = lane & 31;          // = MFMA col = w-row index base
    const int kb   = lane >> 5;          // k-half / w-interleave selector
    const int a    = l31 & 15;           // atom index within a-group
    const int o    = wv * 2 + (l31 >> 4);
    const int oa   = wv * 32 + l31;      // this lane's (o,a) flat

    // ---- conv: wave owns co-tile wv; votes -> vt registers (f16x2 packed)
    f16x2 vt[8][8];   // [d][r-pair]; vt[d][j] = votes at r=2j,2j+1
    {
        f16x8 bf[9];
        const _Float16* wp = wt + (size_t)oa * 144 + kb * 8;
        #pragma unroll
        for (int s = 0; s < 9; ++s) bf[s] = *(const f16x8*)(wp + s * 16);

        #pragma unroll 2
        for (int d = 0; d < 8; ++d) {
            f32x16 acc = {};
            #pragma unroll
            for (int s = 0; s < 9; ++s) {
                const int kh = s / 3, kw = s - 3 * (s / 3);
                const _Float16* ap = &u.xs[kh][l31 + kw][d * 16 + kb * 8];
                f16x4 lo = *(const f16x4*)(ap);
                f16x4 hi = *(const f16x4*)(ap + 4);
                f16x8 af = __builtin_shufflevector(lo, hi, 0, 1, 2, 3, 4, 5, 6, 7);
                acc = __builtin_amdgcn_mfma_f32_32x32x16_f16(af, bf[s], acc, 0, 0, 0);
            }
            #pragma unroll
            for (int j = 0; j < 8; ++j)
                vt[d][j] = f16x2{(_Float16)acc[2 * j], (_Float16)acc[2 * j + 1]};
        }
    }
    __syncthreads();   // xs dead; routing aux region may now be used

    const float bias_t = bias[oa];
    const int iA = t / 30, wA = t - iA * 30;   // phase-A mapping (t<240)

    float pre[16];     // this lane's preact for its 16 w's (r-indexed)
    float scale = 0.f;

    for (int it = 0; it < 3; ++it) {
        // ---- Phase A (it>0): route = softmax_o(logits); threads (i,w)
        if (it > 0) {
            if (t < 240) {
                float l[16], m = -1e30f;
                #pragma unroll
                for (int oo = 0; oo < 16; ++oo) {
                    l[oo] = u.rt.logits[(iA * 16 + oo) * 31 + wA];
                    m = fmaxf(m, l[oo]);
                }
                float ssum = 0.f;
                #pragma unroll
                for (int oo = 0; oo < 16; ++oo) { l[oo] = __expf(l[oo] - m); ssum += l[oo]; }
                float inv = 1.f / ssum;
                #pragma unroll
                for (int oo = 0; oo < 16; ++oo)
                    u.rt.route16[(iA * 16 + oo) * 30 + wA] = (_Float16)(l[oo] * inv);
            }
            __syncthreads();
        }

        // ---- Phase B: pre[r] = bias + sum_i route[i][o][w(r)] * vt[i][r]
        #pragma unroll
        for (int r = 0; r < 16; ++r) pre[r] = bias_t;
        if (it == 0) {
            // softmax(0) = 1/16 exactly
            #pragma unroll
            for (int i = 0; i < 8; ++i)
                #pragma unroll
                for (int r = 0; r < 16; ++r)
                    pre[r] = fmaf(0.0625f, (float)vt[i][r >> 1][r & 1], pre[r]);
        } else {
            #pragma unroll
            for (int i = 0; i < 8; ++i) {
                const _Float16* rr = &u.rt.route16[(i * 16 + o) * 30 + 4 * kb];
                #pragma unroll
                for (int r = 0; r < 16; ++r) {
                    const int wb = (r & 3) + 8 * (r >> 2);   // + 4*kb via rr base
                    pre[r] = fmaf((float)rr[wb], (float)vt[i][r >> 1][r & 1], pre[r]);
                }
            }
        }
        // ---- squash: s2 over this lane's valid w + kb-partner's half
        float s2 = 0.f;
        #pragma unroll
        for (int r = 0; r < 16; ++r) {
            const int wr = (r & 3) + 8 * (r >> 2) + 4 * kb;
            if (r < 14) s2 = fmaf(pre[r], pre[r], s2);
            else if (wr < 30) s2 = fmaf(pre[r], pre[r], s2);  // kb=0: r=14,15 valid
        }
        s2 += __shfl_xor(s2, 32);
        scale = s2 / ((1.f + s2) * sqrtf(s2 + 1e-7f));

        // ---- Phase C (it<2): logits[i][o][w] (+)= sum_a vt*act ; butterfly over a
        if (it < 2) {
            #pragma unroll
            for (int r = 0; r < 16; ++r) {
                const int wr = (r & 3) + 8 * (r >> 2) + 4 * kb;
                const float act_r = scale * pre[r];
                #pragma unroll
                for (int i = 0; i < 8; ++i) {
                    float dsum = (float)vt[i][r >> 1][r & 1] * act_r;
                    dsum += __shfl_xor(dsum, 1);
                    dsum += __shfl_xor(dsum, 2);
                    dsum += __shfl_xor(dsum, 4);
                    dsum += __shfl_xor(dsum, 8);
                    // one writer lane per (i,o,w); skip w>=30
                    if (a == ((i * 16 + r) & 15) && wr < 30) {
                        float* Lp = &u.rt.logits[(i * 16 + o) * 31 + wr];
                        if (it == 0) *Lp = dsum; else *Lp += dsum;
                    }
                }
            }
            __syncthreads();
        }
    }

    // ---- output: out[b,h,w,o,a]; lanes consecutive oa -> 1KB/wave/instr
    float* ob = out + (size_t)((b * 30 + h) * 30) * 256;
    #pragma unroll
    for (int r = 0; r < 16; ++r) {
        const int wr = (r & 3) + 8 * (r >> 2) + 4 * kb;
        if (wr < 30) ob[wr * 256 + oa] = scale * pre[r];
    }
}

extern "C" void kernel_launch(void* const* d_in, const int* in_sizes, int n_in,
                              void* d_out, int out_size, void* d_ws, size_t ws_size,
                              hipStream_t stream)
{
    const float* x    = (const float*)d_in[0];  // [32,32,32,8,16] (raw-reshape view)
    const float* Wt   = (const float*)d_in[1];  // [16,3,3,1,256] = [144][256]
    const float* bias = (const float*)d_in[2];  // [16,16,1,1]
    float* out = (float*)d_out;                 // [32,30,30,16,16]
    _Float16* wt_h = (_Float16*)d_ws;           // [256][144] fp16 = 73,728 B

    prep_wt_kernel<<<dim3(144), 256, 0, stream>>>(Wt, wt_h);
    fused_kernel<<<dim3(30, 32), 512, 0, stream>>>(x, wt_h, bias, out);
}

// Round 12
// 207.474 us; speedup vs baseline: 1.2818x; 1.2818x over previous
//
#include <hip/hip_runtime.h>
#include <hip/hip_bf16.h>

typedef float    f32x4  __attribute__((ext_vector_type(4)));
typedef float    f32x16 __attribute__((ext_vector_type(16)));
typedef _Float16 f16x8  __attribute__((ext_vector_type(8)));
typedef _Float16 f16x4  __attribute__((ext_vector_type(4)));
typedef _Float16 f16x2  __attribute__((ext_vector_type(2)));

#define XP 132   // xs plane-pitch: row stride 66 words === 2 mod 32 -> 2-way (free)

// ---------------------------------------------------------------------------
// Kernel 0: W [144][256] f32 -> wt [co(256)][tap(9)][kd(16)] fp16
// k' = tap*16 + kd ordering, matching the A-side fragment reads.
// ---------------------------------------------------------------------------
__global__ __launch_bounds__(256) void prep_wt_kernel(
    const float* __restrict__ W, _Float16* __restrict__ wt)
{
    const int k = blockIdx.x;      // 0..143 ; kd = k/9, tap = k%9
    const int t = threadIdx.x;     // co
    wt[t * 144 + (k % 9) * 16 + (k / 9)] = (_Float16)W[k * 256 + t];
}

// ---------------------------------------------------------------------------
// Fused kernel: block = (b,h), 512 threads. Conv via MFMA; votes stay in
// REGISTERS (each lane's MFMA acc = votes[all d][its 16 w][its co]).
// ALL vt indices compile-time (full unroll) -> true VGPR residency.
// ---------------------------------------------------------------------------
__global__ __launch_bounds__(512, 2) void fused_kernel(
    const float* __restrict__ x, const _Float16* __restrict__ wt,
    const float* __restrict__ bias, float* __restrict__ out)
{
    const int h = blockIdx.x;   // 30
    const int b = blockIdx.y;   // 32
    const int t = threadIdx.x;  // 0..511

    __shared__ union {
        _Float16 xs[3][36][XP];             // 28,512 B (conv phase)
        struct {                            // routing phase
            float    logits[8 * 16 * 31];   // 15,872 B (pitch 31)
            _Float16 route16[8 * 16 * 30];  //  7,680 B
        } rt;
    } u;

    // ---- stage x: rows h..h+2, 32 cols, 128 planes; fp16, plane-innermost
    {
        const float* xb = x + (size_t)b * 131072;
        for (int j = t; j < 3 * 4 * XP; j += 512) {      // zero cols 32..35
            int r = j / (4 * XP), rem = j - r * (4 * XP);
            int c = rem / XP, p = rem - c * XP;
            u.xs[r][32 + c][p] = (_Float16)0.f;
        }
        #pragma unroll
        for (int j = 0; j < 6; ++j) {
            int idx = t + j * 512;          // 0..3071 float4 granules
            int p   = idx / 24;             // plane (d*16+kd)
            int rem = idx - p * 24;
            int r   = rem >> 3;             // row 0..2
            int c4  = rem & 7;              // col quad
            f32x4 v = *(const f32x4*)(xb + p * 1024 + (h + r) * 32 + c4 * 4);
            u.xs[r][c4 * 4 + 0][p] = (_Float16)v[0];
            u.xs[r][c4 * 4 + 1][p] = (_Float16)v[1];
            u.xs[r][c4 * 4 + 2][p] = (_Float16)v[2];
            u.xs[r][c4 * 4 + 3][p] = (_Float16)v[3];
        }
    }
    __syncthreads();

    const int lane = t & 63, wv = t >> 6;
    const int l31  = lane & 31;          // = MFMA col = w-row index base
    const int kb   = lane >> 5;          // k-half / w-interleave selector
    const int a    = l31 & 15;           // atom index within a-group
    const int o    = wv * 2 + (l31 >> 4);
    const int oa   = wv * 32 + l31;      // this lane's (o,a) flat

    // ---- conv: wave owns co-tile wv; votes -> vt registers (f16x2 packed)
    f16x2 vt[8][8];   // [d][r-pair] — every access below is compile-time indexed
    {
        f16x8 bf[9];
        const _Float16* wp = wt + (size_t)oa * 144 + kb * 8;
        #pragma unroll
        for (int s = 0; s < 9; ++s) bf[s] = *(const f16x8*)(wp + s * 16);

        #pragma unroll   // FULL unroll: d must be compile-time (rule #20)
        for (int d = 0; d < 8; ++d) {
            f32x16 acc = {};
            #pragma unroll
            for (int s = 0; s < 9; ++s) {
                const int kh = s / 3, kw = s - 3 * (s / 3);
                const _Float16* ap = &u.xs[kh][l31 + kw][d * 16 + kb * 8];
                f16x4 lo = *(const f16x4*)(ap);
                f16x4 hi = *(const f16x4*)(ap + 4);
                f16x8 af = __builtin_shufflevector(lo, hi, 0, 1, 2, 3, 4, 5, 6, 7);
                acc = __builtin_amdgcn_mfma_f32_32x32x16_f16(af, bf[s], acc, 0, 0, 0);
            }
            #pragma unroll
            for (int j = 0; j < 8; ++j)
                vt[d][j] = f16x2{(_Float16)acc[2 * j], (_Float16)acc[2 * j + 1]};
        }
    }
    __syncthreads();   // xs dead; routing aux region may now be used

    const float bias_t = bias[oa];
    const int iA = t / 30, wA = t - iA * 30;   // phase-A mapping (t<240)

    float pre[16];     // this lane's preact for its 16 w's (r-indexed)
    float scale = 0.f;

    for (int it = 0; it < 3; ++it) {
        // ---- Phase A (it>0): route = softmax_o(logits); threads (i,w)
        if (it > 0) {
            if (t < 240) {
                float l[16], m = -1e30f;
                #pragma unroll
                for (int oo = 0; oo < 16; ++oo) {
                    l[oo] = u.rt.logits[(iA * 16 + oo) * 31 + wA];
                    m = fmaxf(m, l[oo]);
                }
                float ssum = 0.f;
                #pragma unroll
                for (int oo = 0; oo < 16; ++oo) { l[oo] = __expf(l[oo] - m); ssum += l[oo]; }
                float inv = 1.f / ssum;
                #pragma unroll
                for (int oo = 0; oo < 16; ++oo)
                    u.rt.route16[(iA * 16 + oo) * 30 + wA] = (_Float16)(l[oo] * inv);
            }
            __syncthreads();
        }

        // ---- Phase B: pre[r] = bias + sum_i route[i][o][w(r)] * vt[i][r]
        #pragma unroll
        for (int r = 0; r < 16; ++r) pre[r] = bias_t;
        if (it == 0) {
            // softmax(0) = 1/16 exactly
            #pragma unroll
            for (int i = 0; i < 8; ++i)
                #pragma unroll
                for (int r = 0; r < 16; ++r)
                    pre[r] = fmaf(0.0625f, (float)vt[i][r >> 1][r & 1], pre[r]);
        } else {
            #pragma unroll
            for (int i = 0; i < 8; ++i) {
                const _Float16* rr = &u.rt.route16[(i * 16 + o) * 30 + 4 * kb];
                #pragma unroll
                for (int r = 0; r < 16; ++r) {
                    const int wb = (r & 3) + 8 * (r >> 2);   // + 4*kb via rr base
                    pre[r] = fmaf((float)rr[wb], (float)vt[i][r >> 1][r & 1], pre[r]);
                }
            }
        }
        // ---- squash: s2 over this lane's valid w + kb-partner's half
        float s2 = 0.f;
        #pragma unroll
        for (int r = 0; r < 16; ++r) {
            const int wr = (r & 3) + 8 * (r >> 2) + 4 * kb;
            if (r < 14) s2 = fmaf(pre[r], pre[r], s2);
            else if (wr < 30) s2 = fmaf(pre[r], pre[r], s2);  // kb=0: r=14,15 valid
        }
        s2 += __shfl_xor(s2, 32);
        scale = s2 / ((1.f + s2) * sqrtf(s2 + 1e-7f));

        // ---- Phase C (it<2): logits[i][o][w] (+)= sum_a vt*act ; butterfly over a
        if (it < 2) {
            #pragma unroll
            for (int r = 0; r < 16; ++r) {
                const int wr = (r & 3) + 8 * (r >> 2) + 4 * kb;
                const float act_r = scale * pre[r];
                #pragma unroll
                for (int i = 0; i < 8; ++i) {
                    float dsum = (float)vt[i][r >> 1][r & 1] * act_r;
                    dsum += __shfl_xor(dsum, 1);
                    dsum += __shfl_xor(dsum, 2);
                    dsum += __shfl_xor(dsum, 4);
                    dsum += __shfl_xor(dsum, 8);
                    // one writer lane per (i,o,w); skip w>=30
                    if (a == ((i * 16 + r) & 15) && wr < 30) {
                        float* Lp = &u.rt.logits[(i * 16 + o) * 31 + wr];
                        if (it == 0) *Lp = dsum; else *Lp += dsum;
                    }
                }
            }
            __syncthreads();
        }
    }

    // ---- output: out[b,h,w,o,a]; lanes consecutive oa -> 1KB/wave/instr
    float* ob = out + (size_t)((b * 30 + h) * 30) * 256;
    #pragma unroll
    for (int r = 0; r < 16; ++r) {
        const int wr = (r & 3) + 8 * (r >> 2) + 4 * kb;
        if (wr < 30) ob[wr * 256 + oa] = scale * pre[r];
    }
}

extern "C" void kernel_launch(void* const* d_in, const int* in_sizes, int n_in,
                              void* d_out, int out_size, void* d_ws, size_t ws_size,
                              hipStream_t stream)
{
    const float* x    = (const float*)d_in[0];  // [32,32,32,8,16] (raw-reshape view)
    const float* Wt   = (const float*)d_in[1];  // [16,3,3,1,256] = [144][256]
    const float* bias = (const float*)d_in[2];  // [16,16,1,1]
    float* out = (float*)d_out;                 // [32,30,30,16,16]
    _Float16* wt_h = (_Float16*)d_ws;           // [256][144] fp16 = 73,728 B

    prep_wt_kernel<<<dim3(144), 256, 0, stream>>>(Wt, wt_h);
    fused_kernel<<<dim3(30, 32), 512, 0, stream>>>(x, wt_h, bias, out);
}

// Round 13
// 204.607 us; speedup vs baseline: 1.2998x; 1.0140x over previous
//
#include <hip/hip_runtime.h>
#include <hip/hip_bf16.h>

typedef float    f32x4  __attribute__((ext_vector_type(4)));
typedef float    f32x16 __attribute__((ext_vector_type(16)));
typedef _Float16 f16x8  __attribute__((ext_vector_type(8)));
typedef _Float16 f16x4  __attribute__((ext_vector_type(4)));
typedef _Float16 f16x2  __attribute__((ext_vector_type(2)));

#define XP 132   // xs plane-pitch: row stride 66 words === 2 mod 32 (2-way = free); 8B-aligned rows

// ---------------------------------------------------------------------------
// Kernel 0: W [144][256] f32 -> wt [co(256)][tap(9)][kd(16)] fp16
// ---------------------------------------------------------------------------
__global__ __launch_bounds__(256) void prep_wt_kernel(
    const float* __restrict__ W, _Float16* __restrict__ wt)
{
    const int k = blockIdx.x;      // 0..143 ; kd = k/9, tap = k%9
    const int t = threadIdx.x;     // co
    wt[t * 144 + (k % 9) * 16 + (k / 9)] = (_Float16)W[k * 256 + t];
}

// ---------------------------------------------------------------------------
// Fused kernel: block = (b,h), 512 threads. Votes register-resident.
// Phase C via 15-shuffle transpose-reduce (lane a ends with r=a sum).
// ---------------------------------------------------------------------------
__global__ __launch_bounds__(512, 4) void fused_kernel(
    const float* __restrict__ x, const _Float16* __restrict__ wt,
    const float* __restrict__ bias, float* __restrict__ out)
{
    const int h = blockIdx.x;   // 30
    const int b = blockIdx.y;   // 32
    const int t = threadIdx.x;  // 0..511

    __shared__ union {
        _Float16 xs[3][36][XP];             // 28,512 B (conv phase)
        struct {                            // routing phase
            float    logits[8 * 16 * 31];   // 15,872 B (pitch 31)
            _Float16 route16[8 * 16 * 32];  //  8,192 B (pitch 32: 8B-aligned rows)
        } rt;
    } u;

    // ---- stage x: rows h..h+2, 32 cols, 128 planes; plane-pair packed b32 writes
    {
        const float* xb = x + (size_t)b * 131072;
        #pragma unroll
        for (int j = 0; j < 3; ++j) {
            int q   = t + j * 512;          // 0..1535 plane-pair granules
            int p0  = (q / 24) * 2;         // even plane
            int rem = q - (q / 24) * 24;
            int r   = rem >> 3;             // row 0..2
            int c4  = rem & 7;              // col quad
            f32x4 v0 = *(const f32x4*)(xb + p0 * 1024 + (h + r) * 32 + c4 * 4);
            f32x4 v1 = *(const f32x4*)(xb + (p0 + 1) * 1024 + (h + r) * 32 + c4 * 4);
            #pragma unroll
            for (int c = 0; c < 4; ++c)
                *(f16x2*)&u.xs[r][c4 * 4 + c][p0] = f16x2{(_Float16)v0[c], (_Float16)v1[c]};
        }
    }
    __syncthreads();

    const int lane = t & 63, wv = t >> 6;
    const int l31  = lane & 31;          // = MFMA col / conv w index
    const int kb   = lane >> 5;          // k-half / w-interleave selector
    const int a    = l31 & 15;           // atom index within a-group
    const int o    = wv * 2 + (l31 >> 4);
    const int oa   = wv * 32 + l31;      // this lane's (o,a) flat

    // ---- conv: wave owns co-tile wv; votes -> vt registers (f16x2 packed)
    f16x2 vt[8][8];   // [d][r-pair] — all compile-time indexed
    {
        f16x8 bf[9];
        const _Float16* wp = wt + (size_t)oa * 144 + kb * 8;
        #pragma unroll
        for (int s = 0; s < 9; ++s) bf[s] = *(const f16x8*)(wp + s * 16);

        #pragma unroll
        for (int d = 0; d < 8; ++d) {
            f32x16 acc = {};
            #pragma unroll
            for (int s = 0; s < 9; ++s) {
                const int kh = s / 3, kw = s - 3 * (s / 3);
                const _Float16* ap = &u.xs[kh][l31 + kw][d * 16 + kb * 8];
                f16x4 lo = *(const f16x4*)(ap);
                f16x4 hi = *(const f16x4*)(ap + 4);
                f16x8 af = __builtin_shufflevector(lo, hi, 0, 1, 2, 3, 4, 5, 6, 7);
                acc = __builtin_amdgcn_mfma_f32_32x32x16_f16(af, bf[s], acc, 0, 0, 0);
            }
            #pragma unroll
            for (int j = 0; j < 8; ++j)
                vt[d][j] = f16x2{(_Float16)acc[2 * j], (_Float16)acc[2 * j + 1]};
        }
    }
    __syncthreads();   // xs dead; rt region may now be used

    const float bias_t = bias[oa];
    const int iA = t / 30, wA = t - iA * 30;   // phase-A mapping (t<240)
    const int b0 = a & 1, b1 = (a >> 1) & 1, b2 = (a >> 2) & 1, b3 = a >> 3;
    const int wr_a = (a & 3) + 8 * (a >> 2) + 4 * kb;   // phase-C write w

    float pre[16];
    float scale = 0.f;

    #pragma unroll
    for (int it = 0; it < 3; ++it) {
        // ---- Phase A (it>0): route = softmax_o(logits); threads (i,w)
        if (it > 0) {
            if (t < 240) {
                float l[16], m = -1e30f;
                #pragma unroll
                for (int oo = 0; oo < 16; ++oo) {
                    l[oo] = u.rt.logits[(iA * 16 + oo) * 31 + wA];
                    m = fmaxf(m, l[oo]);
                }
                float ssum = 0.f;
                #pragma unroll
                for (int oo = 0; oo < 16; ++oo) { l[oo] = __expf(l[oo] - m); ssum += l[oo]; }
                float inv = 1.f / ssum;
                #pragma unroll
                for (int oo = 0; oo < 16; ++oo)
                    u.rt.route16[(iA * 16 + oo) * 32 + wA] = (_Float16)(l[oo] * inv);
            }
            __syncthreads();
        }

        // ---- Phase B: pre[r] = bias + sum_i route[i][o][wr(r)] * vt[i][r]
        #pragma unroll
        for (int r = 0; r < 16; ++r) pre[r] = bias_t;
        if (it == 0) {
            #pragma unroll
            for (int i = 0; i < 8; ++i)
                #pragma unroll
                for (int r = 0; r < 16; ++r)
                    pre[r] = fmaf(0.0625f, (float)vt[i][r >> 1][r & 1], pre[r]);
        } else {
            #pragma unroll
            for (int i = 0; i < 8; ++i) {
                const int rbase = (i * 16 + o) * 32 + 4 * kb;
                #pragma unroll
                for (int q = 0; q < 4; ++q) {
                    f16x4 rq = *(const f16x4*)&u.rt.route16[rbase + 8 * q];
                    #pragma unroll
                    for (int j = 0; j < 4; ++j) {
                        const int r = (q << 2) | j;
                        pre[r] = fmaf((float)rq[j], (float)vt[i][r >> 1][r & 1], pre[r]);
                    }
                }
            }
        }
        // ---- squash: s2 over valid w (this half) + kb-partner half
        float s2 = 0.f;
        #pragma unroll
        for (int r = 0; r < 16; ++r) {
            const int wr = (r & 3) + 8 * (r >> 2) + 4 * kb;
            if (r < 14) s2 = fmaf(pre[r], pre[r], s2);
            else if (wr < 30) s2 = fmaf(pre[r], pre[r], s2);
        }
        s2 += __shfl_xor(s2, 32);
        scale = s2 / ((1.f + s2) * sqrtf(s2 + 1e-7f));

        // ---- Phase C (it<2): transpose-reduce over a; lane a ends with r=a
        if (it < 2) {
            float actf[16];
            #pragma unroll
            for (int r = 0; r < 16; ++r) actf[r] = scale * pre[r];
            #pragma unroll
            for (int i = 0; i < 8; ++i) {
                float c0[16];
                #pragma unroll
                for (int r = 0; r < 16; ++r)
                    c0[r] = (float)vt[i][r >> 1][r & 1] * actf[r];
                float c1[8];
                #pragma unroll
                for (int j = 0; j < 8; ++j) {
                    float sent = b0 ? c0[2 * j] : c0[2 * j + 1];
                    float keep = b0 ? c0[2 * j + 1] : c0[2 * j];
                    c1[j] = keep + __shfl_xor(sent, 1);
                }
                float c2[4];
                #pragma unroll
                for (int j = 0; j < 4; ++j) {
                    float sent = b1 ? c1[2 * j] : c1[2 * j + 1];
                    float keep = b1 ? c1[2 * j + 1] : c1[2 * j];
                    c2[j] = keep + __shfl_xor(sent, 2);
                }
                float c3[2];
                #pragma unroll
                for (int j = 0; j < 2; ++j) {
                    float sent = b2 ? c2[2 * j] : c2[2 * j + 1];
                    float keep = b2 ? c2[2 * j + 1] : c2[2 * j];
                    c3[j] = keep + __shfl_xor(sent, 4);
                }
                float sent = b3 ? c3[0] : c3[1];
                float keep = b3 ? c3[1] : c3[0];
                float tot  = keep + __shfl_xor(sent, 8);
                if (wr_a < 30) {
                    float* Lp = &u.rt.logits[(i * 16 + o) * 31 + wr_a];
                    if (it == 0) *Lp = tot; else *Lp += tot;
                }
            }
            __syncthreads();
        }
    }

    // ---- output: out[b,h,w,o,a]; lanes consecutive oa -> 1KB/wave/instr
    float* ob = out + (size_t)((b * 30 + h) * 30) * 256;
    #pragma unroll
    for (int r = 0; r < 16; ++r) {
        const int wr = (r & 3) + 8 * (r >> 2) + 4 * kb;
        if (wr < 30) ob[wr * 256 + oa] = scale * pre[r];
    }
}

extern "C" void kernel_launch(void* const* d_in, const int* in_sizes, int n_in,
                              void* d_out, int out_size, void* d_ws, size_t ws_size,
                              hipStream_t stream)
{
    const float* x    = (const float*)d_in[0];  // [32,32,32,8,16] (raw-reshape view)
    const float* Wt   = (const float*)d_in[1];  // [16,3,3,1,256] = [144][256]
    const float* bias = (const float*)d_in[2];  // [16,16,1,1]
    float* out = (float*)d_out;                 // [32,30,30,16,16]
    _Float16* wt_h = (_Float16*)d_ws;           // [256][144] fp16 = 73,728 B

    prep_wt_kernel<<<dim3(144), 256, 0, stream>>>(Wt, wt_h);
    fused_kernel<<<dim3(30, 32), 512, 0, stream>>>(x, wt_h, bias, out);
}

// Round 14
// 75.869 us; speedup vs baseline: 3.5052x; 2.6969x over previous
//
#include <hip/hip_runtime.h>
#include <hip/hip_bf16.h>

typedef float    f32x4  __attribute__((ext_vector_type(4)));
typedef float    f32x16 __attribute__((ext_vector_type(16)));
typedef _Float16 f16x8  __attribute__((ext_vector_type(8)));
typedef _Float16 f16x4  __attribute__((ext_vector_type(4)));
typedef _Float16 f16x2  __attribute__((ext_vector_type(2)));

#define VP 258   // vlds co-pitch: lane stride 129 words === 1 mod 32 (phase C), consecutive h16 (phase B)
#define XP 132   // xs plane-pitch: A-frag lane stride 66 words === 2 mod 32 -> 2-way (free)
#define AP 258   // act pitch, same arithmetic as VP

// ---------------------------------------------------------------------------
// Kernel 0: W [144][256] f32 -> wt [co(256)][tap(9)][kd(16)] fp16
// ---------------------------------------------------------------------------
__global__ __launch_bounds__(256) void prep_wt_kernel(
    const float* __restrict__ W, _Float16* __restrict__ wt)
{
    const int k = blockIdx.x;      // 0..143 ; kd = k/9, tap = k%9
    const int t = threadIdx.x;     // co
    wt[t * 144 + (k % 9) * 16 + (k / 9)] = (_Float16)W[k * 256 + t];
}

// ---------------------------------------------------------------------------
// Fused kernel: block = (b,h) via XCD-swizzled id, 1024 threads / 16 waves.
// Conv: wave = (co-tile, d-half), 36 MFMA each; votes -> vlds (LDS).
// Routing: B = (oa, w-quarter) all 1024; A/C = 240 threads, logits in regs.
// ---------------------------------------------------------------------------
__global__ __launch_bounds__(1024, 4) void fused_kernel(
    const float* __restrict__ x, const _Float16* __restrict__ wt,
    const float* __restrict__ bias, float* __restrict__ out)
{
    // XCD swizzle: 960 blocks = 8 XCDs x 120; same-b blocks cluster per XCD
    const int bid = blockIdx.x;
    const int wid = (bid & 7) * 120 + (bid >> 3);
    const int b = wid / 30, h = wid - 30 * b;
    const int t = threadIdx.x;  // 0..1023

    __shared__ _Float16 vlds[8 * 30 * VP];          // 123,840 B
    __shared__ union {
        _Float16 xs[3][36][XP];                     // 28,512 B (conv phase)
        struct {                                    // routing phase
            _Float16 route16[8 * 16 * 32];          //  8,192 B
            _Float16 act16[30 * AP];                // 15,480 B
            float    s2buf[4][256];                 //  4,096 B  (sum 27,768)
        } rt;
    } u;                                            // total 152,352 B

    // ---- stage x (T14: issue loads early, write late); plane-pair packed
    {
        const float* xb = x + (size_t)b * 131072;
        f32x4 v0[2], v1[2];
        int p0s[2], rs[2], c4s[2];
        #pragma unroll
        for (int j = 0; j < 2; ++j) {
            int q = t + j * 1024;
            bool ok = q < 1536;
            int qq = ok ? q : 0;
            int g  = qq / 24;
            p0s[j] = g * 2;
            int rem = qq - g * 24;
            rs[j] = rem >> 3; c4s[j] = rem & 7;
            if (ok) {
                v0[j] = *(const f32x4*)(xb + p0s[j] * 1024 + (h + rs[j]) * 32 + c4s[j] * 4);
                v1[j] = *(const f32x4*)(xb + (p0s[j] + 1) * 1024 + (h + rs[j]) * 32 + c4s[j] * 4);
            }
        }
        if (t < 768) {      // zero-fill cols 32..35 (plane pairs)
            int r = t / 256, rem = t - r * 256;
            int c = rem >> 6, pz = (rem & 63) * 2;
            *(f16x2*)&u.xs[r][32 + c][pz] = f16x2{(_Float16)0.f, (_Float16)0.f};
        }
        #pragma unroll
        for (int j = 0; j < 2; ++j) {
            if (t + j * 1024 < 1536) {
                #pragma unroll
                for (int c = 0; c < 4; ++c)
                    *(f16x2*)&u.xs[rs[j]][c4s[j] * 4 + c][p0s[j]] =
                        f16x2{(_Float16)v0[j][c], (_Float16)v1[j][c]};
            }
        }
    }
    __syncthreads();

    const int lane = t & 63, wv = t >> 6;   // wv 0..15
    const int l31  = lane & 31;             // MFMA col / conv w index
    const int kb   = lane >> 5;
    const int ct   = wv >> 1, dh = wv & 1;  // co-tile 0..7, d-half 0..1
    const int oaC  = ct * 32 + l31;         // conv-phase oa

    // ---- conv: wave = (ct, dh): 4 d's x 9 K-steps; votes -> vlds
    {
        f16x8 bf[9];
        const _Float16* wp = wt + (size_t)oaC * 144 + kb * 8;
        #pragma unroll
        for (int s = 0; s < 9; ++s) bf[s] = *(const f16x8*)(wp + s * 16);

        #pragma unroll
        for (int dd = 0; dd < 4; ++dd) {
            f32x16 acc = {};
            #pragma unroll
            for (int s = 0; s < 9; ++s) {
                const int kh = s / 3, kw = s - 3 * (s / 3);
                const _Float16* ap = &u.xs[kh][l31 + kw][dh * 64 + dd * 16 + kb * 8];
                f16x4 lo = *(const f16x4*)(ap);
                f16x4 hi = *(const f16x4*)(ap + 4);
                f16x8 af = __builtin_shufflevector(lo, hi, 0, 1, 2, 3, 4, 5, 6, 7);
                acc = __builtin_amdgcn_mfma_f32_32x32x16_f16(af, bf[s], acc, 0, 0, 0);
            }
            const int d = dh * 4 + dd;
            #pragma unroll
            for (int r = 0; r < 16; ++r) {
                const int wr = (r & 3) + 8 * (r >> 2) + 4 * kb;
                if (wr < 30) vlds[(d * 30 + wr) * VP + oaC] = (_Float16)acc[r];
            }
        }
    }
    __syncthreads();

    // ---- routing
    const int oa = t & 255, wq = t >> 8;    // phase-B mapping: (oa, w-quarter)
    const int o  = oa >> 4;
    const int wbase = wq * 8;
    const int nw = (wq == 3) ? 6 : 8;
    const float bias_t = bias[oa];
    const int iA = t / 30, wA = t - iA * 30;  // phase-A/C mapping (t<240)

    float lreg[16];
    #pragma unroll
    for (int oo = 0; oo < 16; ++oo) lreg[oo] = 0.f;

    float pre[8];
    float scale = 0.f;

    for (int it = 0; it < 3; ++it) {
        // ---- Phase A (it>0): route = softmax_o(lreg); threads (i,w)
        if (it > 0) {
            if (t < 240) {
                float m = lreg[0];
                #pragma unroll
                for (int oo = 1; oo < 16; ++oo) m = fmaxf(m, lreg[oo]);
                float e[16], ssum = 0.f;
                #pragma unroll
                for (int oo = 0; oo < 16; ++oo) { e[oo] = __expf(lreg[oo] - m); ssum += e[oo]; }
                float inv = 1.f / ssum;
                #pragma unroll
                for (int oo = 0; oo < 16; ++oo)
                    u.rt.route16[(iA * 16 + oo) * 32 + wA] = (_Float16)(e[oo] * inv);
            }
            __syncthreads();
        }

        // ---- Phase B: thread (oa, wq): pre[w] over its w-quarter
        #pragma unroll
        for (int w = 0; w < 8; ++w) pre[w] = bias_t;
        if (it == 0) {
            #pragma unroll
            for (int i = 0; i < 8; ++i) {
                const _Float16* vrow = &vlds[(i * 30 + wbase) * VP + oa];
                #pragma unroll
                for (int w = 0; w < 8; ++w)
                    if (w < nw) pre[w] = fmaf(0.0625f, (float)vrow[w * VP], pre[w]);
            }
        } else {
            #pragma unroll
            for (int i = 0; i < 8; ++i) {
                const _Float16* vrow = &vlds[(i * 30 + wbase) * VP + oa];
                const _Float16* rr   = &u.rt.route16[(i * 16 + o) * 32 + wbase];
                #pragma unroll
                for (int w = 0; w < 8; ++w)
                    if (w < nw) pre[w] = fmaf((float)rr[w], (float)vrow[w * VP], pre[w]);
            }
        }
        float s2p = 0.f;
        #pragma unroll
        for (int w = 0; w < 8; ++w)
            if (w < nw) s2p = fmaf(pre[w], pre[w], s2p);
        u.rt.s2buf[wq][oa] = s2p;
        __syncthreads();
        float s2 = u.rt.s2buf[0][oa] + u.rt.s2buf[1][oa]
                 + u.rt.s2buf[2][oa] + u.rt.s2buf[3][oa];
        scale = s2 / ((1.f + s2) * sqrtf(s2 + 1e-7f));

        if (it < 2) {
            #pragma unroll
            for (int w = 0; w < 8; ++w)
                if (w < nw) u.rt.act16[(wbase + w) * AP + oa] = (_Float16)(scale * pre[w]);
            __syncthreads();
            // ---- Phase C: thread (i,w) t<240: lreg[o] (+)= sum_a v*act
            if (t < 240) {
                const _Float16* vrow = &vlds[(iA * 30 + wA) * VP];
                const _Float16* arow = &u.rt.act16[wA * AP];
                #pragma unroll
                for (int oo = 0; oo < 16; ++oo) {
                    float s = 0.f;
                    #pragma unroll
                    for (int k = 0; k < 8; ++k) {
                        f16x2 v2 = *(const f16x2*)&vrow[oo * 16 + 2 * k];
                        f16x2 a2 = *(const f16x2*)&arow[oo * 16 + 2 * k];
                        s = fmaf((float)v2[0], (float)a2[0], s);
                        s = fmaf((float)v2[1], (float)a2[1], s);
                    }
                    if (it == 0) lreg[oo] = s; else lreg[oo] += s;
                }
            }
            // next A (same 240 threads) / its barrier separates act from rewrite
        }
    }

    // ---- output: out[b,h,w,o,a]; lanes consecutive oa -> coalesced
    float* ob = out + (size_t)((b * 30 + h) * 30) * 256;
    #pragma unroll
    for (int w = 0; w < 8; ++w)
        if (w < nw) ob[(wbase + w) * 256 + oa] = scale * pre[w];
}

extern "C" void kernel_launch(void* const* d_in, const int* in_sizes, int n_in,
                              void* d_out, int out_size, void* d_ws, size_t ws_size,
                              hipStream_t stream)
{
    const float* x    = (const float*)d_in[0];  // [32,32,32,8,16] (raw-reshape view)
    const float* Wt   = (const float*)d_in[1];  // [16,3,3,1,256] = [144][256]
    const float* bias = (const float*)d_in[2];  // [16,16,1,1]
    float* out = (float*)d_out;                 // [32,30,30,16,16]
    _Float16* wt_h = (_Float16*)d_ws;           // [256][144] fp16 = 73,728 B

    prep_wt_kernel<<<dim3(144), 256, 0, stream>>>(Wt, wt_h);
    fused_kernel<<<dim3(960), 1024, 0, stream>>>(x, wt_h, bias, out);
}